// Round 3
// baseline (645.303 us; speedup 1.0000x reference)
//
#include <hip/hip_runtime.h>

#define S 512
#define B 128
#define H 1024

#define KG 16          // k-groups (two-stage calc_u)
#define KR 64          // k per group: KG*KR == H
#define BPG 8          // b per stage-1 block
#define BG (B / BPG)   // 16 b-groups

// ---------------------------------------------------------------------------
// calc_u stage 1: part[kg][b][h] = sum_{k in group kg} hidden[b][k]*W[k][h].
// 256 blocks x 256 threads; thread owns 4 h (float4 W loads, coalesced 1KB/
// wave-instr); hidden loads are wave-uniform -> scalar pipe. W read 16x total
// (64 MB, L2). unroll 8 for VMEM depth at 1 wave/SIMD.
// ---------------------------------------------------------------------------
__global__ __launch_bounds__(256) void calc_u_part(const float* __restrict__ hidden,
                                                   const float* __restrict__ W,
                                                   float* __restrict__ part) {
    const int t  = threadIdx.x;
    const int kg = blockIdx.x & (KG - 1);
    const int bg = blockIdx.x >> 4;
    const int b0 = bg * BPG;
    const int h4 = t * 4;
    const int k0 = kg * KR;

    float4 acc[BPG];
#pragma unroll
    for (int j = 0; j < BPG; ++j) acc[j] = make_float4(0.f, 0.f, 0.f, 0.f);

#pragma unroll 8
    for (int kk = 0; kk < KR; ++kk) {
        const int k = k0 + kk;
        const float4 w = *reinterpret_cast<const float4*>(W + (size_t)k * H + h4);
#pragma unroll
        for (int j = 0; j < BPG; ++j) {
            const float hb = hidden[(size_t)(b0 + j) * H + k];  // uniform
            acc[j].x = fmaf(hb, w.x, acc[j].x);
            acc[j].y = fmaf(hb, w.y, acc[j].y);
            acc[j].z = fmaf(hb, w.z, acc[j].z);
            acc[j].w = fmaf(hb, w.w, acc[j].w);
        }
    }
#pragma unroll
    for (int j = 0; j < BPG; ++j)
        *reinterpret_cast<float4*>(part + ((size_t)kg * B + (b0 + j)) * H + h4) = acc[j];
}

// Stage 2: u = sum_kg part (float4), and zero the softmax completion counters
// (stream order guarantees this lands before calc_scores_softmax reads them).
__global__ __launch_bounds__(256) void calc_u_reduce(const float* __restrict__ part,
                                                     float* __restrict__ u,
                                                     int* __restrict__ cnt) {
    const int idx4 = blockIdx.x * 256 + threadIdx.x;  // float4 index into [B*H/4)
    const float4* __restrict__ p4 = reinterpret_cast<const float4*>(part);
    float4 s = p4[idx4];
#pragma unroll
    for (int kg = 1; kg < KG; ++kg) {
        float4 v = p4[(size_t)kg * (B * H / 4) + idx4];
        s.x += v.x; s.y += v.y; s.z += v.z; s.w += v.w;
    }
    reinterpret_cast<float4*>(u)[idx4] = s;
    if (blockIdx.x == 0 && threadIdx.x < B) cnt[threadIdx.x] = 0;
}

// Fallback single-stage calc_u (tiny workspace only).
__global__ __launch_bounds__(256) void calc_u_fallback(const float* __restrict__ hidden,
                                                       const float* __restrict__ W,
                                                       float* __restrict__ u,
                                                       int* __restrict__ cnt) {
    const int h  = (blockIdx.x & 3) * 256 + threadIdx.x;
    const int bb = blockIdx.x >> 2;
    const float* __restrict__ h0p = hidden + (size_t)bb * H;
    const float* __restrict__ h1p = hidden + (size_t)(bb + 64) * H;
    float acc0 = 0.f, acc1 = 0.f;
#pragma unroll 16
    for (int k = 0; k < H; ++k) {
        float w = W[(size_t)k * H + h];
        acc0 = fmaf(h0p[k], w, acc0);
        acc1 = fmaf(h1p[k], w, acc1);
    }
    u[(size_t)bb * H + h] = acc0;
    u[(size_t)(bb + 64) * H + h] = acc1;
    if (blockIdx.x == 0 && threadIdx.x < B) cnt[threadIdx.x] = 0;
}

// ---------------------------------------------------------------------------
// Fused scores + softmax. Wave w: b = w&127, sg = w>>7; covers s in
// [sg*8, sg*8+8). u[b] held in 16 VGPRs (read once per 32 KB of enc).
// Block's 4 waves = 4 consecutive b at the same s -> 16 KB contiguous enc
// per j. After storing its 8 scores each wave bumps cnt[b]; the 64th
// (last) wave for b performs the row softmax in-wave. Deterministic:
// scores are fixed, performer identity doesn't affect output.
// b_attn never computed: constant per row, cancels in softmax.
// ---------------------------------------------------------------------------
__global__ __launch_bounds__(256) void calc_scores_softmax(const float* __restrict__ enc,
                                                           const float* __restrict__ u,
                                                           float* __restrict__ scores,
                                                           int* __restrict__ cnt,
                                                           float* __restrict__ out) {
    const int wid  = threadIdx.x >> 6;
    const int lane = threadIdx.x & 63;
    const int w  = blockIdx.x * 4 + wid;   // 0..8191
    const int b  = w & (B - 1);
    const int sg = w >> 7;                 // 0..63
    const int s0 = sg * 8;

    const float4* __restrict__ u4 = reinterpret_cast<const float4*>(u + (size_t)b * H);
    const float4 uu0 = u4[lane];
    const float4 uu1 = u4[64 + lane];
    const float4 uu2 = u4[128 + lane];
    const float4 uu3 = u4[192 + lane];

    float acc[8];
#pragma unroll
    for (int j = 0; j < 8; ++j) {
        const float4* __restrict__ e4 =
            reinterpret_cast<const float4*>(enc + ((size_t)(s0 + j) * B + b) * H);
        const float4 e0 = e4[lane];
        const float4 e1 = e4[64 + lane];
        const float4 e2 = e4[128 + lane];
        const float4 e3 = e4[192 + lane];
        float a = e0.x * uu0.x + e0.y * uu0.y + e0.z * uu0.z + e0.w * uu0.w;
        a = fmaf(e1.x, uu1.x, a); a = fmaf(e1.y, uu1.y, a);
        a = fmaf(e1.z, uu1.z, a); a = fmaf(e1.w, uu1.w, a);
        a = fmaf(e2.x, uu2.x, a); a = fmaf(e2.y, uu2.y, a);
        a = fmaf(e2.z, uu2.z, a); a = fmaf(e2.w, uu2.w, a);
        a = fmaf(e3.x, uu3.x, a); a = fmaf(e3.y, uu3.y, a);
        a = fmaf(e3.z, uu3.z, a); a = fmaf(e3.w, uu3.w, a);
        acc[j] = a;
    }
#pragma unroll
    for (int j = 0; j < 8; ++j)
#pragma unroll
        for (int off = 32; off >= 1; off >>= 1)
            acc[j] += __shfl_xor(acc[j], off, 64);

    if (lane == 0) {
        float4* sp = reinterpret_cast<float4*>(scores + (size_t)b * S + s0);
        sp[0] = make_float4(acc[0], acc[1], acc[2], acc[3]);
        sp[1] = make_float4(acc[4], acc[5], acc[6], acc[7]);
    }
    __threadfence();   // release scores before signaling
    int old = 0;
    if (lane == 0) old = atomicAdd(&cnt[b], 1);
    old = __shfl(old, 0, 64);
    if (old == 63) {   // last wave for this b: do the softmax
        __threadfence();  // acquire other waves' scores
        const float4* rp = reinterpret_cast<const float4*>(scores + (size_t)b * S + lane * 8);
        const float4 v0 = rp[0];
        const float4 v1 = rp[1];
        float m = fmaxf(fmaxf(fmaxf(v0.x, v0.y), fmaxf(v0.z, v0.w)),
                        fmaxf(fmaxf(v1.x, v1.y), fmaxf(v1.z, v1.w)));
#pragma unroll
        for (int off = 32; off >= 1; off >>= 1)
            m = fmaxf(m, __shfl_xor(m, off, 64));
        const float e0 = __expf(v0.x - m), e1 = __expf(v0.y - m),
                    e2 = __expf(v0.z - m), e3 = __expf(v0.w - m),
                    e4 = __expf(v1.x - m), e5 = __expf(v1.y - m),
                    e6 = __expf(v1.z - m), e7 = __expf(v1.w - m);
        float sum = ((e0 + e1) + (e2 + e3)) + ((e4 + e5) + (e6 + e7));
#pragma unroll
        for (int off = 32; off >= 1; off >>= 1)
            sum += __shfl_xor(sum, off, 64);
        const float inv = 1.f / sum;
        float4* op = reinterpret_cast<float4*>(out + (size_t)b * S + lane * 8);
        op[0] = make_float4(e0 * inv, e1 * inv, e2 * inv, e3 * inv);
        op[1] = make_float4(e4 * inv, e5 * inv, e6 * inv, e7 * inv);
    }
}

extern "C" void kernel_launch(void* const* d_in, const int* in_sizes, int n_in,
                              void* d_out, int out_size, void* d_ws, size_t ws_size,
                              hipStream_t stream) {
    const float* hidden = (const float*)d_in[0];   // [1,B,H]
    const float* enc    = (const float*)d_in[1];   // [S,B,H]
    const float* W      = (const float*)d_in[2];   // [H,H]
    // d_in[3] = b_attn: unused — constant per row, cancels in softmax.

    float* u      = (float*)d_ws;                       // B*H floats
    float* scores = u + (size_t)B * H;                  // B*S floats
    float* part   = scores + (size_t)B * S;             // KG*B*H floats
    int*   cnt    = (int*)(part + (size_t)KG * B * H);  // B ints
    float* out    = (float*)d_out;                      // [B,1,S]

    const size_t need_full =
        ((size_t)B * H + (size_t)B * S + (size_t)KG * B * H) * sizeof(float) + B * sizeof(int);
    if (ws_size >= need_full) {
        calc_u_part  <<<KG * BG, 256, 0, stream>>>(hidden, W, part);
        calc_u_reduce<<<(B * H / 4) / 256, 256, 0, stream>>>(part, u, cnt);
    } else {
        // small-ws fallback: cnt right after scores
        cnt = (int*)(scores + (size_t)B * S);
        calc_u_fallback<<<256, 256, 0, stream>>>(hidden, W, u, cnt);
    }
    calc_scores_softmax<<<2048, 256, 0, stream>>>(enc, u, scores, cnt, out);
}

// Round 4
// 60.996 us; speedup vs baseline: 10.5794x; 10.5794x over previous
//
#include <hip/hip_runtime.h>

#define S 512
#define B 128
#define H 1024

#define KG 16          // k-groups (two-stage calc_u)
#define KR 64          // k per group: KG*KR == H
#define BPG 8          // b per stage-1 block
#define BG (B / BPG)   // 16 b-groups

// ---------------------------------------------------------------------------
// calc_u stage 1: part[kg][b][h] = sum_{k in kg-group} hidden[b][k]*W[k][h].
// 256 blocks x 256 threads; thread owns 4 h (float4 W loads, 1KB/wave-instr
// coalesced); hidden loads wave-uniform -> scalar pipe. Deterministic.
// ---------------------------------------------------------------------------
__global__ __launch_bounds__(256) void calc_u_part(const float* __restrict__ hidden,
                                                   const float* __restrict__ W,
                                                   float* __restrict__ part) {
    const int t  = threadIdx.x;
    const int kg = blockIdx.x & (KG - 1);
    const int bg = blockIdx.x >> 4;
    const int b0 = bg * BPG;
    const int h4 = t * 4;
    const int k0 = kg * KR;

    float4 acc[BPG];
#pragma unroll
    for (int j = 0; j < BPG; ++j) acc[j] = make_float4(0.f, 0.f, 0.f, 0.f);

#pragma unroll 8
    for (int kk = 0; kk < KR; ++kk) {
        const int k = k0 + kk;
        const float4 w = *reinterpret_cast<const float4*>(W + (size_t)k * H + h4);
#pragma unroll
        for (int j = 0; j < BPG; ++j) {
            const float hb = hidden[(size_t)(b0 + j) * H + k];  // uniform
            acc[j].x = fmaf(hb, w.x, acc[j].x);
            acc[j].y = fmaf(hb, w.y, acc[j].y);
            acc[j].z = fmaf(hb, w.z, acc[j].z);
            acc[j].w = fmaf(hb, w.w, acc[j].w);
        }
    }
#pragma unroll
    for (int j = 0; j < BPG; ++j)
        *reinterpret_cast<float4*>(part + ((size_t)kg * B + (b0 + j)) * H + h4) = acc[j];
}

// Stage 2: u = sum_kg part, float4 form (1/4 the VMEM instructions).
__global__ __launch_bounds__(256) void calc_u_reduce(const float* __restrict__ part,
                                                     float* __restrict__ u) {
    const int idx4 = blockIdx.x * 256 + threadIdx.x;  // float4 index in [B*H/4)
    const float4* __restrict__ p4 = reinterpret_cast<const float4*>(part);
    float4 s = p4[idx4];
#pragma unroll
    for (int kg = 1; kg < KG; ++kg) {
        float4 v = p4[(size_t)kg * (B * H / 4) + idx4];
        s.x += v.x; s.y += v.y; s.z += v.z; s.w += v.w;
    }
    reinterpret_cast<float4*>(u)[idx4] = s;
}

// Fallback single-stage calc_u (tiny workspace only).
__global__ __launch_bounds__(256) void calc_u_fallback(const float* __restrict__ hidden,
                                                       const float* __restrict__ W,
                                                       float* __restrict__ u) {
    const int h  = (blockIdx.x & 3) * 256 + threadIdx.x;
    const int bb = blockIdx.x >> 2;
    const float* __restrict__ h0p = hidden + (size_t)bb * H;
    const float* __restrict__ h1p = hidden + (size_t)(bb + 64) * H;
    float acc0 = 0.f, acc1 = 0.f;
#pragma unroll 16
    for (int k = 0; k < H; ++k) {
        float w = W[(size_t)k * H + h];
        acc0 = fmaf(h0p[k], w, acc0);
        acc1 = fmaf(h1p[k], w, acc1);
    }
    u[(size_t)bb * H + h] = acc0;
    u[(size_t)(bb + 64) * H + h] = acc1;
}

// ---------------------------------------------------------------------------
// calc_scores: scores[b][s] = dot(enc[s][b][:], u[b][:]).
// Wave w: b = w&127, sg = w>>7; covers s in [sg*8, sg*8+8). u[b] in 16 VGPRs
// (read once per 32 KB of enc). Block's 4 waves = 4 consecutive b at the same
// s -> 16 KB contiguous enc per j-iter. 2048 blocks = 8 blocks/CU. No fences,
// no atomics — softmax is a separate kernel (cross-XCD signaling is ~100ns/
// wave serialized at TCC; measured 13x regression in R2).
// ---------------------------------------------------------------------------
__global__ __launch_bounds__(256) void calc_scores(const float* __restrict__ enc,
                                                   const float* __restrict__ u,
                                                   float* __restrict__ scores) {
    const int wid  = threadIdx.x >> 6;
    const int lane = threadIdx.x & 63;
    const int w  = blockIdx.x * 4 + wid;   // 0..8191
    const int b  = w & (B - 1);
    const int sg = w >> 7;                 // 0..63
    const int s0 = sg * 8;

    const float4* __restrict__ u4 = reinterpret_cast<const float4*>(u + (size_t)b * H);
    const float4 uu0 = u4[lane];
    const float4 uu1 = u4[64 + lane];
    const float4 uu2 = u4[128 + lane];
    const float4 uu3 = u4[192 + lane];

    float acc[8];
#pragma unroll
    for (int j = 0; j < 8; ++j) {
        const float4* __restrict__ e4 =
            reinterpret_cast<const float4*>(enc + ((size_t)(s0 + j) * B + b) * H);
        const float4 e0 = e4[lane];
        const float4 e1 = e4[64 + lane];
        const float4 e2 = e4[128 + lane];
        const float4 e3 = e4[192 + lane];
        float a = e0.x * uu0.x + e0.y * uu0.y + e0.z * uu0.z + e0.w * uu0.w;
        a = fmaf(e1.x, uu1.x, a); a = fmaf(e1.y, uu1.y, a);
        a = fmaf(e1.z, uu1.z, a); a = fmaf(e1.w, uu1.w, a);
        a = fmaf(e2.x, uu2.x, a); a = fmaf(e2.y, uu2.y, a);
        a = fmaf(e2.z, uu2.z, a); a = fmaf(e2.w, uu2.w, a);
        a = fmaf(e3.x, uu3.x, a); a = fmaf(e3.y, uu3.y, a);
        a = fmaf(e3.z, uu3.z, a); a = fmaf(e3.w, uu3.w, a);
        acc[j] = a;
    }
#pragma unroll
    for (int j = 0; j < 8; ++j)
#pragma unroll
        for (int off = 32; off >= 1; off >>= 1)
            acc[j] += __shfl_xor(acc[j], off, 64);

    if (lane == 0) {
        float4* sp = reinterpret_cast<float4*>(scores + (size_t)b * S + s0);
        sp[0] = make_float4(acc[0], acc[1], acc[2], acc[3]);
        sp[1] = make_float4(acc[4], acc[5], acc[6], acc[7]);
    }
}

// ---------------------------------------------------------------------------
// softmax over s per b. b_attn never computed: constant per row -> cancels.
// ---------------------------------------------------------------------------
__global__ __launch_bounds__(256) void softmax_rows(const float* __restrict__ scores,
                                                    float* __restrict__ out) {
    const int b = blockIdx.x;
    const int t = threadIdx.x;
    const int wid = t >> 6, lane = t & 63;
    const float* __restrict__ row = scores + (size_t)b * S;
    float v0 = row[t];
    float v1 = row[t + 256];

    __shared__ float sm[4], ss[4];

    float m = fmaxf(v0, v1);
#pragma unroll
    for (int off = 32; off >= 1; off >>= 1)
        m = fmaxf(m, __shfl_xor(m, off, 64));
    if (lane == 0) sm[wid] = m;
    __syncthreads();
    m = fmaxf(fmaxf(sm[0], sm[1]), fmaxf(sm[2], sm[3]));

    float e0 = __expf(v0 - m);
    float e1 = __expf(v1 - m);
    float sum = e0 + e1;
#pragma unroll
    for (int off = 32; off >= 1; off >>= 1)
        sum += __shfl_xor(sum, off, 64);
    if (lane == 0) ss[wid] = sum;
    __syncthreads();
    sum = ss[0] + ss[1] + ss[2] + ss[3];

    const float inv = 1.f / sum;
    out[(size_t)b * S + t]       = e0 * inv;
    out[(size_t)b * S + t + 256] = e1 * inv;
}

extern "C" void kernel_launch(void* const* d_in, const int* in_sizes, int n_in,
                              void* d_out, int out_size, void* d_ws, size_t ws_size,
                              hipStream_t stream) {
    const float* hidden = (const float*)d_in[0];   // [1,B,H]
    const float* enc    = (const float*)d_in[1];   // [S,B,H]
    const float* W      = (const float*)d_in[2];   // [H,H]
    // d_in[3] = b_attn: unused — constant per row, cancels in softmax.

    float* u      = (float*)d_ws;                       // B*H floats
    float* scores = u + (size_t)B * H;                  // B*S floats
    float* part   = scores + (size_t)B * S;             // KG*B*H floats
    float* out    = (float*)d_out;                      // [B,1,S]

    const size_t need_full =
        ((size_t)B * H + (size_t)B * S + (size_t)KG * B * H) * sizeof(float);
    if (ws_size >= need_full) {
        calc_u_part  <<<KG * BG, 256, 0, stream>>>(hidden, W, part);
        calc_u_reduce<<<(B * H / 4) / 256, 256, 0, stream>>>(part, u);
    } else {
        calc_u_fallback<<<256, 256, 0, stream>>>(hidden, W, u);
    }
    calc_scores <<<2048, 256, 0, stream>>>(enc, u, scores);
    softmax_rows<<<128,  256, 0, stream>>>(scores, out);
}